// Round 10
// baseline (248.970 us; speedup 1.0000x reference)
//
#include <hip/hip_runtime.h>
#include <math.h>

#define BB   16
#define RR   4096
#define NC   80          // foreground classes
#define KK   300
#define DD   100
#define CCAP 512         // per-(image,class) candidate cap (expected ~118, sigma ~11)
#define CAP  16384       // per-image kept-candidate cap (expected ~8800)
#define LCAP 32          // per-(block,class) local cap in kernel A (lambda ~7.4)
#define NBLK 16          // kernel-A blocks per image (4096 rows / 256)
#define NW   5           // 5*64 = 320 >= KK bitmask words
#define PAD  (NW * 64)   // 320 padded rank slots
#define HBINS 1280       // score histogram bins (used: 1128)
#define HPT   5          // bins per scan-thread (1280/256)
#define BIN0  0x7A99u    // (0x3D4CCCCD >> 15): bin of score==0.05f
#define ZCNT  20512      // ints to zero in A: g_cnt(16)+pad(16)+g_hist(20480)

typedef unsigned long long ull;

// 32-byte packed candidate record: key + decoded box in one cache-line slot.
struct Rec { ull key; ull _pad; float4 bb; };

__device__ __forceinline__ float4 decode_box(const float4 pr, const float4 rg) {
    float dx = rg.x / 10.0f;
    float dy = rg.y / 10.0f;
    float dw = fminf(rg.z / 5.0f, 4.135166556742356f);
    float dh = fminf(rg.w / 5.0f, 4.135166556742356f);
    float w  = pr.z - pr.x + 1.0f;
    float h  = pr.w - pr.y + 1.0f;
    float cx = pr.x + 0.5f * w;
    float cy = pr.y + 0.5f * h;
    float pcx = dx * w + cx;
    float pcy = dy * h + cy;
    float pw  = expf(dw) * w;
    float ph  = expf(dh) * h;
    float x1 = pcx - 0.5f * pw;
    float y1 = pcy - 0.5f * ph;
    float x2 = pcx + 0.5f * pw - 1.0f;
    float y2 = pcy + 0.5f * ph - 1.0f;
    x1 = fminf(fmaxf(x1, 0.0f), 1332.0f);
    y1 = fminf(fmaxf(y1, 0.0f), 799.0f);
    x2 = fminf(fmaxf(x2, 0.0f), 1332.0f);
    y2 = fminf(fmaxf(y2, 0.0f), 799.0f);
    return make_float4(x1, y1, x2, y2);
}

// ---- Kernel A: one lane per row, streaming softmax + decode-at-source emit ----
// All 64 lanes of every wave own distinct rows (full issue efficiency; expf is
// ~40-instr libm so issue slots are the scarce resource). Three streams per row:
//   1) serial fmax (exact), 2) serial left-fold expf sum in class order 0..80
//   (bit-identical fold to all prior rounds), 3) emit pass with conservative
//   log prefilter; exact p = expf(x-m)/s on ~2 survivors/row.
// No per-thread array -> no scratch spills. Grid 256 x 256 (1 block/CU).
__global__ __launch_bounds__(256) void softmax_cand_kernel(
        const float* __restrict__ logits,
        const float* __restrict__ box_reg,
        const float* __restrict__ proposals,
        Rec*         __restrict__ cand_rec,  // [BB*NC][NBLK][LCAP]
        int*         __restrict__ cnt_blk,   // [BB*NC][NBLK]
        int*         __restrict__ zeros) {   // ws head: ZCNT ints to clear
    __shared__ int lhist[NC];

    const int tid = threadIdx.x;
    const int gid = blockIdx.x * 256 + tid;
    const int b   = blockIdx.x >> 4;          // 16 blocks per image
    const int blk = blockIdx.x & 15;
    const int row = gid;                      // one thread per row

    if (gid < ZCNT) zeros[gid] = 0;

    if (tid < NC) lhist[tid] = 0;
    __syncthreads();

    const float* rp = logits + (size_t)row * 81;

    // pass 1: max (exact regardless of order; order kept anyway)
    float m0 = -1e30f;
    #pragma unroll
    for (int q = 0; q < 20; ++q) {
        float4 t = *(const float4*)(rp + 4 * q);
        m0 = fmaxf(m0, t.x); m0 = fmaxf(m0, t.y);
        m0 = fmaxf(m0, t.z); m0 = fmaxf(m0, t.w);
    }
    m0 = fmaxf(m0, rp[80]);

    // pass 2: serial left-fold expf sum in class order 0..80 (bit-identical)
    float s0 = 0.0f;
    #pragma unroll
    for (int q = 0; q < 20; ++q) {
        float4 t = *(const float4*)(rp + 4 * q);    // L2-resident re-read
        s0 += expf(t.x - m0); s0 += expf(t.y - m0);
        s0 += expf(t.z - m0); s0 += expf(t.w - m0);
    }
    s0 += expf(rp[80] - m0);

    // pass 3: emit with conservative prefilter (margin >> libm ULP error)
    const float thr = logf(0.05f * s0) - 0.01f;
    const float4 pr = *(const float4*)(proposals + (size_t)row * 4);
    const unsigned rlow = (unsigned)(row & 4095);

    #pragma unroll
    for (int q = 0; q < 20; ++q) {
        float4 t = *(const float4*)(rp + 4 * q);    // L2-resident re-read
        #pragma unroll
        for (int k = 0; k < 4; ++k) {
            int c = 4 * q + k;
            if (c == 0) continue;                   // background class
            float x = (k == 0) ? t.x : (k == 1) ? t.y : (k == 2) ? t.z : t.w;
            if (x - m0 > thr) {
                float p = expf(x - m0) / s0;        // exact expression as always
                if (p > 0.05f) {
                    int ci  = c - 1;
                    int pos = atomicAdd(&lhist[ci], 1);
                    if (pos < LCAP) {
                        size_t slot = ((size_t)(b * NC + ci) * NBLK + blk) * LCAP + pos;
                        const float4 rg = *(const float4*)(box_reg + (size_t)row * 324 + (size_t)(ci + 1) * 4);
                        Rec* rr = &cand_rec[slot];
                        rr->key = ((ull)__float_as_uint(p) << 32) | (unsigned)(~rlow);
                        rr->bb  = decode_box(pr, rg);
                    }
                }
            }
        }
    }
    {   // element 80 = class 80 (ci 79)
        float x = rp[80];
        if (x - m0 > thr) {
            float p = expf(x - m0) / s0;
            if (p > 0.05f) {
                int ci  = 79;
                int pos = atomicAdd(&lhist[ci], 1);
                if (pos < LCAP) {
                    size_t slot = ((size_t)(b * NC + ci) * NBLK + blk) * LCAP + pos;
                    const float4 rg = *(const float4*)(box_reg + (size_t)row * 324 + (size_t)(ci + 1) * 4);
                    Rec* rr = &cand_rec[slot];
                    rr->key = ((ull)__float_as_uint(p) << 32) | (unsigned)(~rlow);
                    rr->bb  = decode_box(pr, rg);
                }
            }
        }
    }
    __syncthreads();

    if (tid < NC) {
        int h = lhist[tid]; if (h > LCAP) h = LCAP;
        cnt_blk[(b * NC + tid) * NBLK + blk] = h;
    }
}

// ---- Kernel B: per (image,class): rank-by-count sort (keys) + bb from packed
//      records, parallel NMS mask build, wave-0 greedy scan + append. ----
__global__ __launch_bounds__(256) void percls_kernel(
        const Rec*   __restrict__ cand_rec,
        const int*   __restrict__ cnt_blk,
        ull*         __restrict__ img_keys,  // [BB][CAP]
        unsigned*    __restrict__ img_meta,  // [BB][CAP]  (ci<<12 | r)
        int*         __restrict__ g_cnt,     // [BB]
        int*         __restrict__ g_hist) {  // [BB][HBINS]
    #pragma clang fp contract(off)
    __shared__ ull   keys[CCAP];                       // 4 KB   unsorted keys
    __shared__ int   gidx[CCAP];                       // 2 KB   slot -> A-segment index
    __shared__ ull   skey[PAD];                        // 2.56 KB rank-ordered keys
    __shared__ float bx1[PAD], by1[PAD], bx2[PAD], by2[PAD], bar[PAD];  // 6.4 KB
    __shared__ ull   supm[PAD * NW];                   // 12.8 KB per-row suppression masks
    __shared__ int   sbase[NBLK + 1];

    const int bid = blockIdx.x;     // 0..1279
    const int b   = bid / NC;
    const int ci  = bid % NC;
    const int tid = threadIdx.x;
    const size_t rbase = (size_t)bid * (NBLK * LCAP);

    // wave-0 parallel prefix of the 16 per-A-block counts
    if (tid < 64) {
        int cnt = (tid < NBLK) ? cnt_blk[bid * NBLK + tid] : 0;
        int sc  = cnt;
        #pragma unroll
        for (int d = 1; d < NBLK; d <<= 1) {
            int o = __shfl_up(sc, d, NBLK);
            if ((tid & (NBLK - 1)) >= d) sc += o;
        }
        if (tid < NBLK) sbase[tid + 1] = sc;
        if (tid == 0)   sbase[0] = 0;
    }
    __syncthreads();

    int M = sbase[NBLK]; if (M > CCAP) M = CCAP;

    // flattened parallel segment compaction (keys; lines stay hot for bb reads)
    for (int idx = tid; idx < NBLK * LCAP; idx += 256) {
        int seg = idx / LCAP, j = idx - seg * LCAP;
        int lo  = sbase[seg], c = sbase[seg + 1] - lo;
        if (j < c) {
            int slot = lo + j;
            if (slot < CCAP) {
                keys[slot] = cand_rec[rbase + idx].key;
                gidx[slot] = idx;
            }
        }
    }
    __syncthreads();

    const int N = (M < KK) ? M : KK;

    // rank-by-count + bb gather + scatter (unique keys => exact descending sort)
    for (int i = tid; i < M; i += 256) {
        ull ki = keys[i];
        int rank = 0;
        for (int j = 0; j < M; ++j) rank += (keys[j] > ki);  // broadcast LDS reads
        if (rank < PAD) {
            skey[rank] = ki;
            float4 bb = cand_rec[rbase + gidx[i]].bb;
            bx1[rank] = bb.x; by1[rank] = bb.y; bx2[rank] = bb.z; by2[rank] = bb.w;
            bar[rank] = (bb.z - bb.x + 1.0f) * (bb.w - bb.y + 1.0f);
        }
    }
    __syncthreads();

    // parallel NMS mask build: thread per row i, IoU vs all j>i (identical math)
    for (int i = tid; i < N; i += 256) {
        ull mw[NW];
        #pragma unroll
        for (int w = 0; w < NW; ++w) mw[w] = 0ULL;
        const float ax1 = bx1[i], ay1 = by1[i],
                    ax2 = bx2[i], ay2 = by2[i], aar = bar[i];
        for (int j = i + 1; j < N; ++j) {
            float ltx = fmaxf(ax1, bx1[j]);
            float lty = fmaxf(ay1, by1[j]);
            float rbx = fminf(ax2, bx2[j]);
            float rby = fminf(ay2, by2[j]);
            float iw  = fmaxf(rbx - ltx + 1.0f, 0.0f);
            float ih  = fmaxf(rby - lty + 1.0f, 0.0f);
            float inter = iw * ih;
            float iou   = inter / ((aar + bar[j]) - inter);
            if (iou > 0.5f) mw[j >> 6] |= 1ULL << (j & 63);
        }
        #pragma unroll
        for (int w = 0; w < NW; ++w) supm[i * NW + w] = mw[w];
    }
    __syncthreads();

    // ---- greedy scan + append: wave 0, masks from LDS ----
    if (tid < 64) {
        const int lane = tid;

        ull keepw[NW];
        #pragma unroll
        for (int w = 0; w < NW; ++w) {
            int lo = w * 64;
            keepw[w] = (N >= lo + 64) ? ~0ULL : (N <= lo ? 0ULL : ((1ULL << (N - lo)) - 1ULL));
        }

        #pragma unroll
        for (int t = 0; t < NW; ++t) {
            if (t * 64 >= N) break;
            const int i = t * 64 + lane;
            ull sp[NW];
            #pragma unroll
            for (int w = 0; w < NW; ++w)
                sp[w] = (i < N) ? supm[i * NW + w] : 0ULL;

            ull rowany = 0ULL;
            #pragma unroll
            for (int w = 0; w < NW; ++w) rowany |= sp[w];
            const ull act = __ballot(rowany != 0ULL);

            ull mloop = keepw[t] & act;
            while (mloop) {
                int l = __builtin_ctzll(mloop);
                if ((keepw[t] >> l) & 1ULL) {
                    #pragma unroll
                    for (int w = 0; w < NW; ++w) {
                        if (w >= t && w * 64 < N)
                            keepw[w] &= ~__shfl(sp[w], l);
                    }
                }
                ull below = (l >= 63) ? ~0ULL : ((1ULL << (l + 1)) - 1ULL);
                mloop = keepw[t] & act & ~below;
            }
        }

        int total = 0;
        #pragma unroll
        for (int w = 0; w < NW; ++w) total += __popcll(keepw[w]);
        int base0 = 0;
        if (lane == 0) base0 = atomicAdd(&g_cnt[b], total);
        base0 = __shfl(base0, 0);

        int acc = 0;
        #pragma unroll
        for (int w = 0; w < NW; ++w) {
            if (w * 64 < N) {
                const ull km = keepw[w];
                const int k2 = w * 64 + lane;
                if ((km >> lane) & 1ULL) {
                    int rank = __popcll(km & ((1ULL << lane) - 1ULL));
                    int pos  = base0 + acc + rank;
                    if (pos < CAP) {
                        ull key = skey[k2];
                        unsigned sb = (unsigned)(key >> 32);
                        unsigned r  = ~(unsigned)(key & 0xFFFFFFFFu);
                        unsigned fi = (unsigned)(ci * KK + k2);
                        img_keys[(size_t)b * CAP + pos] =
                            ((ull)sb << 32) | (unsigned)(~fi);
                        img_meta[(size_t)b * CAP + pos] = ((unsigned)ci << 12) | (r & 4095u);
                        int bin = (int)((sb >> 15) - BIN0);
                        bin = (bin < 0) ? 0 : (bin >= HBINS ? HBINS - 1 : bin);
                        atomicAdd(&g_hist[b * HBINS + bin], 1);
                    }
                }
                acc += __popcll(km);
            }
        }
    }
}

// ---- Kernel C: threshold from prebuilt hist + gather + wave sort + emit (unchanged) ----
__global__ __launch_bounds__(1024) void topd_kernel(
        const ull*      __restrict__ img_keys,
        const unsigned* __restrict__ img_meta,
        const int*      __restrict__ g_cnt,
        const int*      __restrict__ g_hist,
        const float*    __restrict__ box_reg,
        const float*    __restrict__ proposals,
        float*          __restrict__ out) {
    __shared__ int  suf[256];
    __shared__ ull  pk[256];
    __shared__ int  ps[256];
    __shared__ int  sh_cnt, sh_tb;

    const int b   = blockIdx.x;
    const int tid = threadIdx.x;
    int M = g_cnt[b]; if (M > CAP) M = CAP;
    const ull* kp = img_keys + (size_t)b * CAP;
    const int* hh = g_hist + b * HBINS;

    if (tid == 0) { sh_cnt = 0; sh_tb = 0; }
    __syncthreads();

    int h[HPT], tot = 0;
    if (tid < 256) {
        #pragma unroll
        for (int r = 0; r < HPT; ++r) { h[r] = hh[tid * HPT + r]; tot += h[r]; }
        suf[tid] = tot;
    }
    __syncthreads();
    for (int off = 1; off < 256; off <<= 1) {
        int add = 0;
        if (tid < 256 && tid + off < 256) add = suf[tid + off];
        __syncthreads();
        if (tid < 256) suf[tid] += add;
        __syncthreads();
    }
    if (tid < 256) {
        int cum = suf[tid] - tot;
        #pragma unroll
        for (int jj = HPT - 1; jj >= 0; --jj) {
            int prev = cum;
            cum += h[jj];
            if (cum >= DD && prev < DD) sh_tb = tid * HPT + jj;
        }
    }
    __syncthreads();
    const unsigned keyLo = ((unsigned)sh_tb + BIN0) << 15;

    for (int i = tid; i < M; i += 1024) {
        ull key = kp[i];
        if ((unsigned)(key >> 32) >= keyLo) {
            int p = atomicAdd(&sh_cnt, 1);
            if (p < 256) { pk[p] = key; ps[p] = i; }
        }
    }
    __syncthreads();

    if (tid < 64) {
        const int lane  = tid;
        int ngath = sh_cnt; if (ngath > 256) ngath = 256;

        ull k4[4]; int s4[4];
        #pragma unroll
        for (int q = 0; q < 4; ++q) {
            int i = lane + 64 * q;
            bool vld = (i < ngath);
            k4[q] = vld ? pk[i] : 0ULL;
            s4[q] = vld ? ps[i] : -1;
        }

        #pragma unroll
        for (int k = 2; k <= 256; k <<= 1) {
            #pragma unroll
            for (int j = k >> 1; j > 0; j >>= 1) {
                if (j >= 64) {
                    const int qj = j >> 6;
                    #pragma unroll
                    for (int q = 0; q < 4; ++q) {
                        if ((q & qj) == 0 && (q + qj) < 4) {
                            int i0 = lane + 64 * q;
                            bool desc = ((i0 & k) == 0);
                            ull x = k4[q], y = k4[q + qj];
                            bool sw = desc ? (x < y) : (x > y);
                            if (sw) {
                                k4[q] = y; k4[q + qj] = x;
                                int t = s4[q]; s4[q] = s4[q + qj]; s4[q + qj] = t;
                            }
                        }
                    }
                } else {
                    #pragma unroll
                    for (int q = 0; q < 4; ++q) {
                        int i0 = lane + 64 * q;
                        bool desc  = ((i0 & k) == 0);
                        bool lower = ((lane & j) == 0);
                        ull pv = __shfl_xor(k4[q], j);
                        int sv = __shfl_xor(s4[q], j);
                        bool take = (desc == lower) ? (pv > k4[q]) : (pv < k4[q]);
                        if (take) { k4[q] = pv; s4[q] = sv; }
                    }
                }
            }
        }

        #pragma unroll
        for (int q = 0; q < 2; ++q) {
            int p = lane + 64 * q;
            if (p < DD) {
                float s; float4 bb; int label;
                if (p < ngath) {
                    ull key = k4[q];
                    unsigned fi   = ~(unsigned)(key & 0xFFFFFFFFu);
                    unsigned meta = img_meta[(size_t)b * CAP + s4[q]];
                    unsigned rr   = meta & 4095u;
                    unsigned ci   = meta >> 12;
                    s  = __uint_as_float((unsigned)(key >> 32));
                    size_t n = (size_t)b * RR + rr;
                    const float4 pr = *(const float4*)(proposals + n * 4);
                    const float4 rg = *(const float4*)(box_reg + n * 324 + (size_t)(ci + 1) * 4);
                    bb = decode_box(pr, rg);
                    label = (int)(fi / KK) + 1;
                } else {
                    s = -1.0f; bb = make_float4(0.0f, 0.0f, 0.0f, 0.0f); label = 0;
                }
                *(float4*)(out + (size_t)(b * DD + p) * 4) = bb;
                out[(size_t)BB * DD * 4 + b * DD + p] = s;
                out[(size_t)BB * DD * 4 + BB * DD + b * DD + p] = (float)label;
            }
        }
    }
}

extern "C" void kernel_launch(void* const* d_in, const int* in_sizes, int n_in,
                              void* d_out, int out_size, void* d_ws, size_t ws_size,
                              hipStream_t stream) {
    const float* logits    = (const float*)d_in[0];   // [B*R, 81]
    const float* box_reg   = (const float*)d_in[1];   // [B*R, 324]
    const float* proposals = (const float*)d_in[2];   // [B*R, 4]
    float* out = (float*)d_out;

    char* ws = (char*)d_ws;
    int*      g_cnt    = (int*)ws;                    //         64 B
    //        (ws + 64): 64 B reserved (zeroed, unused)
    int*      g_hist   = (int*)(ws + 128);            //     81,920 B (ends     82,048; first ZCNT ints zeroed by A)
    int*      cnt_blk  = (int*)(ws + 82048);          //     81,920 B (ends    163,968; fully overwritten by A)
    Rec*      cand_rec = (Rec*)(ws + 163968);         // 20,971,520 B (ends 21,135,488; 32B-aligned base)
    ull*      img_keys = (ull*)(ws + 21135488);       //  2,097,152 B (ends 23,232,640)
    unsigned* img_meta = (unsigned*)(ws + 23232640);  //  1,048,576 B (ends 24,281,216)

    softmax_cand_kernel<<<(BB * RR) / 256, 256, 0, stream>>>(
        logits, box_reg, proposals, cand_rec, cnt_blk, (int*)ws);
    percls_kernel<<<BB * NC, 256, 0, stream>>>(
        cand_rec, cnt_blk, img_keys, img_meta, g_cnt, g_hist);
    topd_kernel<<<BB, 1024, 0, stream>>>(
        img_keys, img_meta, g_cnt, g_hist, box_reg, proposals, out);
}

// Round 11
// 247.279 us; speedup vs baseline: 1.0068x; 1.0068x over previous
//
#include <hip/hip_runtime.h>
#include <math.h>

#define BB   16
#define RR   4096
#define NC   80          // foreground classes
#define KK   300
#define DD   100
#define CCAP 512         // per-(image,class) candidate cap (expected ~118, sigma ~11)
#define CAP  16384       // per-image kept-candidate cap (expected ~8800)
#define LCAP 32          // per-(block,class) local cap in kernel A (lambda ~7.4)
#define NBLK 16          // kernel-A blocks per image (4096 rows / 256)
#define NW   5           // 5*64 = 320 >= KK bitmask words
#define PAD  (NW * 64)   // 320 padded rank slots
#define HBINS 1280       // score histogram bins (used: 1128)
#define HPT   5          // bins per scan-thread (1280/256)
#define BIN0  0x7A99u    // (0x3D4CCCCD >> 15): bin of score==0.05f
#define ZCNT  20512      // ints to zero in A: g_cnt(16)+pad(16)+g_hist(20480)

typedef unsigned long long ull;

// 32-byte packed candidate record: key + decoded box in one cache-line slot.
struct Rec { ull key; ull _pad; float4 bb; };

__device__ __forceinline__ float4 decode_box(const float4 pr, const float4 rg) {
    float dx = rg.x / 10.0f;
    float dy = rg.y / 10.0f;
    float dw = fminf(rg.z / 5.0f, 4.135166556742356f);
    float dh = fminf(rg.w / 5.0f, 4.135166556742356f);
    float w  = pr.z - pr.x + 1.0f;
    float h  = pr.w - pr.y + 1.0f;
    float cx = pr.x + 0.5f * w;
    float cy = pr.y + 0.5f * h;
    float pcx = dx * w + cx;
    float pcy = dy * h + cy;
    float pw  = expf(dw) * w;
    float ph  = expf(dh) * h;
    float x1 = pcx - 0.5f * pw;
    float y1 = pcy - 0.5f * ph;
    float x2 = pcx + 0.5f * pw - 1.0f;
    float y2 = pcy + 0.5f * ph - 1.0f;
    x1 = fminf(fmaxf(x1, 0.0f), 1332.0f);
    y1 = fminf(fmaxf(y1, 0.0f), 799.0f);
    x2 = fminf(fmaxf(x2, 0.0f), 1332.0f);
    y2 = fminf(fmaxf(y2, 0.0f), 799.0f);
    return make_float4(x1, y1, x2, y2);
}

// ---- Kernel A: one lane per row, row RESIDENT IN REGISTERS ----
// 65536 threads total => at most 1 wave/SIMD; __launch_bounds__(256,1) frees
// the register allocator (up to ~512 VGPR/wave) so v[81] lives in registers:
// no 3-pass L2 re-reads (R10's stall), no spills (R6's bug). Serial max +
// serial left-fold expf sum in class order 0..80 (bit-identical), prefiltered
// emit with exact p = expf(v-m)/s on ~2 survivors/row. All v[] indexing is
// compile-time constant (fully unrolled) -> stays in registers.
__global__ __launch_bounds__(256, 1) void softmax_cand_kernel(
        const float* __restrict__ logits,
        const float* __restrict__ box_reg,
        const float* __restrict__ proposals,
        Rec*         __restrict__ cand_rec,  // [BB*NC][NBLK][LCAP]
        int*         __restrict__ cnt_blk,   // [BB*NC][NBLK]
        int*         __restrict__ zeros) {   // ws head: ZCNT ints to clear
    __shared__ int lhist[NC];

    const int tid = threadIdx.x;
    const int gid = blockIdx.x * 256 + tid;
    const int b   = blockIdx.x >> 4;          // 16 blocks per image
    const int blk = blockIdx.x & 15;
    const int row = gid;                      // one thread per row

    if (gid < ZCNT) zeros[gid] = 0;

    if (tid < NC) lhist[tid] = 0;
    __syncthreads();

    const float* rp = logits + (size_t)row * 81;

    // single memory burst: 20 independent float4 loads + 1 scalar (MLP-20)
    float v[81];
    #pragma unroll
    for (int q = 0; q < 20; ++q) {
        float4 t = *(const float4*)(rp + 4 * q);
        v[4 * q + 0] = t.x; v[4 * q + 1] = t.y;
        v[4 * q + 2] = t.z; v[4 * q + 3] = t.w;
    }
    v[80] = rp[80];

    // serial max (exact)
    float m0 = -1e30f;
    #pragma unroll
    for (int c = 0; c < 81; ++c) m0 = fmaxf(m0, v[c]);

    // serial left-fold expf sum in class order 0..80 (bit-identical fold)
    float s0 = 0.0f;
    #pragma unroll
    for (int c = 0; c < 81; ++c) s0 += expf(v[c] - m0);

    // emit with conservative prefilter (margin >> libm ULP error)
    const float thr = logf(0.05f * s0) - 0.01f;
    const float4 pr = *(const float4*)(proposals + (size_t)row * 4);
    const unsigned rlow = (unsigned)(row & 4095);

    #pragma unroll
    for (int c = 1; c < 81; ++c) {
        if (v[c] - m0 > thr) {
            float p = expf(v[c] - m0) / s0;   // exact expression as always
            if (p > 0.05f) {
                int ci  = c - 1;
                int pos = atomicAdd(&lhist[ci], 1);
                if (pos < LCAP) {
                    size_t slot = ((size_t)(b * NC + ci) * NBLK + blk) * LCAP + pos;
                    const float4 rg = *(const float4*)(box_reg + (size_t)row * 324 + (size_t)(ci + 1) * 4);
                    Rec* rr = &cand_rec[slot];
                    rr->key = ((ull)__float_as_uint(p) << 32) | (unsigned)(~rlow);
                    rr->bb  = decode_box(pr, rg);
                }
            }
        }
    }
    __syncthreads();

    if (tid < NC) {
        int h = lhist[tid]; if (h > LCAP) h = LCAP;
        cnt_blk[(b * NC + tid) * NBLK + blk] = h;
    }
}

// ---- Kernel B: per (image,class): rank-by-count sort (keys) + bb from packed
//      records, parallel NMS mask build, wave-0 greedy scan + append. ----
__global__ __launch_bounds__(256) void percls_kernel(
        const Rec*   __restrict__ cand_rec,
        const int*   __restrict__ cnt_blk,
        ull*         __restrict__ img_keys,  // [BB][CAP]
        unsigned*    __restrict__ img_meta,  // [BB][CAP]  (ci<<12 | r)
        int*         __restrict__ g_cnt,     // [BB]
        int*         __restrict__ g_hist) {  // [BB][HBINS]
    #pragma clang fp contract(off)
    __shared__ ull   keys[CCAP];                       // 4 KB   unsorted keys
    __shared__ int   gidx[CCAP];                       // 2 KB   slot -> A-segment index
    __shared__ ull   skey[PAD];                        // 2.56 KB rank-ordered keys
    __shared__ float bx1[PAD], by1[PAD], bx2[PAD], by2[PAD], bar[PAD];  // 6.4 KB
    __shared__ ull   supm[PAD * NW];                   // 12.8 KB per-row suppression masks
    __shared__ int   sbase[NBLK + 1];

    const int bid = blockIdx.x;     // 0..1279
    const int b   = bid / NC;
    const int ci  = bid % NC;
    const int tid = threadIdx.x;
    const size_t rbase = (size_t)bid * (NBLK * LCAP);

    // wave-0 parallel prefix of the 16 per-A-block counts
    if (tid < 64) {
        int cnt = (tid < NBLK) ? cnt_blk[bid * NBLK + tid] : 0;
        int sc  = cnt;
        #pragma unroll
        for (int d = 1; d < NBLK; d <<= 1) {
            int o = __shfl_up(sc, d, NBLK);
            if ((tid & (NBLK - 1)) >= d) sc += o;
        }
        if (tid < NBLK) sbase[tid + 1] = sc;
        if (tid == 0)   sbase[0] = 0;
    }
    __syncthreads();

    int M = sbase[NBLK]; if (M > CCAP) M = CCAP;

    // flattened parallel segment compaction (keys; lines stay hot for bb reads)
    for (int idx = tid; idx < NBLK * LCAP; idx += 256) {
        int seg = idx / LCAP, j = idx - seg * LCAP;
        int lo  = sbase[seg], c = sbase[seg + 1] - lo;
        if (j < c) {
            int slot = lo + j;
            if (slot < CCAP) {
                keys[slot] = cand_rec[rbase + idx].key;
                gidx[slot] = idx;
            }
        }
    }
    __syncthreads();

    const int N = (M < KK) ? M : KK;

    // rank-by-count + bb gather + scatter (unique keys => exact descending sort)
    for (int i = tid; i < M; i += 256) {
        ull ki = keys[i];
        int rank = 0;
        for (int j = 0; j < M; ++j) rank += (keys[j] > ki);  // broadcast LDS reads
        if (rank < PAD) {
            skey[rank] = ki;
            float4 bb = cand_rec[rbase + gidx[i]].bb;
            bx1[rank] = bb.x; by1[rank] = bb.y; bx2[rank] = bb.z; by2[rank] = bb.w;
            bar[rank] = (bb.z - bb.x + 1.0f) * (bb.w - bb.y + 1.0f);
        }
    }
    __syncthreads();

    // parallel NMS mask build: thread per row i, IoU vs all j>i (identical math)
    for (int i = tid; i < N; i += 256) {
        ull mw[NW];
        #pragma unroll
        for (int w = 0; w < NW; ++w) mw[w] = 0ULL;
        const float ax1 = bx1[i], ay1 = by1[i],
                    ax2 = bx2[i], ay2 = by2[i], aar = bar[i];
        for (int j = i + 1; j < N; ++j) {
            float ltx = fmaxf(ax1, bx1[j]);
            float lty = fmaxf(ay1, by1[j]);
            float rbx = fminf(ax2, bx2[j]);
            float rby = fminf(ay2, by2[j]);
            float iw  = fmaxf(rbx - ltx + 1.0f, 0.0f);
            float ih  = fmaxf(rby - lty + 1.0f, 0.0f);
            float inter = iw * ih;
            float iou   = inter / ((aar + bar[j]) - inter);
            if (iou > 0.5f) mw[j >> 6] |= 1ULL << (j & 63);
        }
        #pragma unroll
        for (int w = 0; w < NW; ++w) supm[i * NW + w] = mw[w];
    }
    __syncthreads();

    // ---- greedy scan + append: wave 0, masks from LDS ----
    if (tid < 64) {
        const int lane = tid;

        ull keepw[NW];
        #pragma unroll
        for (int w = 0; w < NW; ++w) {
            int lo = w * 64;
            keepw[w] = (N >= lo + 64) ? ~0ULL : (N <= lo ? 0ULL : ((1ULL << (N - lo)) - 1ULL));
        }

        #pragma unroll
        for (int t = 0; t < NW; ++t) {
            if (t * 64 >= N) break;
            const int i = t * 64 + lane;
            ull sp[NW];
            #pragma unroll
            for (int w = 0; w < NW; ++w)
                sp[w] = (i < N) ? supm[i * NW + w] : 0ULL;

            ull rowany = 0ULL;
            #pragma unroll
            for (int w = 0; w < NW; ++w) rowany |= sp[w];
            const ull act = __ballot(rowany != 0ULL);

            ull mloop = keepw[t] & act;
            while (mloop) {
                int l = __builtin_ctzll(mloop);
                if ((keepw[t] >> l) & 1ULL) {
                    #pragma unroll
                    for (int w = 0; w < NW; ++w) {
                        if (w >= t && w * 64 < N)
                            keepw[w] &= ~__shfl(sp[w], l);
                    }
                }
                ull below = (l >= 63) ? ~0ULL : ((1ULL << (l + 1)) - 1ULL);
                mloop = keepw[t] & act & ~below;
            }
        }

        int total = 0;
        #pragma unroll
        for (int w = 0; w < NW; ++w) total += __popcll(keepw[w]);
        int base0 = 0;
        if (lane == 0) base0 = atomicAdd(&g_cnt[b], total);
        base0 = __shfl(base0, 0);

        int acc = 0;
        #pragma unroll
        for (int w = 0; w < NW; ++w) {
            if (w * 64 < N) {
                const ull km = keepw[w];
                const int k2 = w * 64 + lane;
                if ((km >> lane) & 1ULL) {
                    int rank = __popcll(km & ((1ULL << lane) - 1ULL));
                    int pos  = base0 + acc + rank;
                    if (pos < CAP) {
                        ull key = skey[k2];
                        unsigned sb = (unsigned)(key >> 32);
                        unsigned r  = ~(unsigned)(key & 0xFFFFFFFFu);
                        unsigned fi = (unsigned)(ci * KK + k2);
                        img_keys[(size_t)b * CAP + pos] =
                            ((ull)sb << 32) | (unsigned)(~fi);
                        img_meta[(size_t)b * CAP + pos] = ((unsigned)ci << 12) | (r & 4095u);
                        int bin = (int)((sb >> 15) - BIN0);
                        bin = (bin < 0) ? 0 : (bin >= HBINS ? HBINS - 1 : bin);
                        atomicAdd(&g_hist[b * HBINS + bin], 1);
                    }
                }
                acc += __popcll(km);
            }
        }
    }
}

// ---- Kernel C: threshold from prebuilt hist + gather + wave sort + emit (unchanged) ----
__global__ __launch_bounds__(1024) void topd_kernel(
        const ull*      __restrict__ img_keys,
        const unsigned* __restrict__ img_meta,
        const int*      __restrict__ g_cnt,
        const int*      __restrict__ g_hist,
        const float*    __restrict__ box_reg,
        const float*    __restrict__ proposals,
        float*          __restrict__ out) {
    __shared__ int  suf[256];
    __shared__ ull  pk[256];
    __shared__ int  ps[256];
    __shared__ int  sh_cnt, sh_tb;

    const int b   = blockIdx.x;
    const int tid = threadIdx.x;
    int M = g_cnt[b]; if (M > CAP) M = CAP;
    const ull* kp = img_keys + (size_t)b * CAP;
    const int* hh = g_hist + b * HBINS;

    if (tid == 0) { sh_cnt = 0; sh_tb = 0; }
    __syncthreads();

    int h[HPT], tot = 0;
    if (tid < 256) {
        #pragma unroll
        for (int r = 0; r < HPT; ++r) { h[r] = hh[tid * HPT + r]; tot += h[r]; }
        suf[tid] = tot;
    }
    __syncthreads();
    for (int off = 1; off < 256; off <<= 1) {
        int add = 0;
        if (tid < 256 && tid + off < 256) add = suf[tid + off];
        __syncthreads();
        if (tid < 256) suf[tid] += add;
        __syncthreads();
    }
    if (tid < 256) {
        int cum = suf[tid] - tot;
        #pragma unroll
        for (int jj = HPT - 1; jj >= 0; --jj) {
            int prev = cum;
            cum += h[jj];
            if (cum >= DD && prev < DD) sh_tb = tid * HPT + jj;
        }
    }
    __syncthreads();
    const unsigned keyLo = ((unsigned)sh_tb + BIN0) << 15;

    for (int i = tid; i < M; i += 1024) {
        ull key = kp[i];
        if ((unsigned)(key >> 32) >= keyLo) {
            int p = atomicAdd(&sh_cnt, 1);
            if (p < 256) { pk[p] = key; ps[p] = i; }
        }
    }
    __syncthreads();

    if (tid < 64) {
        const int lane  = tid;
        int ngath = sh_cnt; if (ngath > 256) ngath = 256;

        ull k4[4]; int s4[4];
        #pragma unroll
        for (int q = 0; q < 4; ++q) {
            int i = lane + 64 * q;
            bool vld = (i < ngath);
            k4[q] = vld ? pk[i] : 0ULL;
            s4[q] = vld ? ps[i] : -1;
        }

        #pragma unroll
        for (int k = 2; k <= 256; k <<= 1) {
            #pragma unroll
            for (int j = k >> 1; j > 0; j >>= 1) {
                if (j >= 64) {
                    const int qj = j >> 6;
                    #pragma unroll
                    for (int q = 0; q < 4; ++q) {
                        if ((q & qj) == 0 && (q + qj) < 4) {
                            int i0 = lane + 64 * q;
                            bool desc = ((i0 & k) == 0);
                            ull x = k4[q], y = k4[q + qj];
                            bool sw = desc ? (x < y) : (x > y);
                            if (sw) {
                                k4[q] = y; k4[q + qj] = x;
                                int t = s4[q]; s4[q] = s4[q + qj]; s4[q + qj] = t;
                            }
                        }
                    }
                } else {
                    #pragma unroll
                    for (int q = 0; q < 4; ++q) {
                        int i0 = lane + 64 * q;
                        bool desc  = ((i0 & k) == 0);
                        bool lower = ((lane & j) == 0);
                        ull pv = __shfl_xor(k4[q], j);
                        int sv = __shfl_xor(s4[q], j);
                        bool take = (desc == lower) ? (pv > k4[q]) : (pv < k4[q]);
                        if (take) { k4[q] = pv; s4[q] = sv; }
                    }
                }
            }
        }

        #pragma unroll
        for (int q = 0; q < 2; ++q) {
            int p = lane + 64 * q;
            if (p < DD) {
                float s; float4 bb; int label;
                if (p < ngath) {
                    ull key = k4[q];
                    unsigned fi   = ~(unsigned)(key & 0xFFFFFFFFu);
                    unsigned meta = img_meta[(size_t)b * CAP + s4[q]];
                    unsigned rr   = meta & 4095u;
                    unsigned ci   = meta >> 12;
                    s  = __uint_as_float((unsigned)(key >> 32));
                    size_t n = (size_t)b * RR + rr;
                    const float4 pr = *(const float4*)(proposals + n * 4);
                    const float4 rg = *(const float4*)(box_reg + n * 324 + (size_t)(ci + 1) * 4);
                    bb = decode_box(pr, rg);
                    label = (int)(fi / KK) + 1;
                } else {
                    s = -1.0f; bb = make_float4(0.0f, 0.0f, 0.0f, 0.0f); label = 0;
                }
                *(float4*)(out + (size_t)(b * DD + p) * 4) = bb;
                out[(size_t)BB * DD * 4 + b * DD + p] = s;
                out[(size_t)BB * DD * 4 + BB * DD + b * DD + p] = (float)label;
            }
        }
    }
}

extern "C" void kernel_launch(void* const* d_in, const int* in_sizes, int n_in,
                              void* d_out, int out_size, void* d_ws, size_t ws_size,
                              hipStream_t stream) {
    const float* logits    = (const float*)d_in[0];   // [B*R, 81]
    const float* box_reg   = (const float*)d_in[1];   // [B*R, 324]
    const float* proposals = (const float*)d_in[2];   // [B*R, 4]
    float* out = (float*)d_out;

    char* ws = (char*)d_ws;
    int*      g_cnt    = (int*)ws;                    //         64 B
    //        (ws + 64): 64 B reserved (zeroed, unused)
    int*      g_hist   = (int*)(ws + 128);            //     81,920 B (ends     82,048; first ZCNT ints zeroed by A)
    int*      cnt_blk  = (int*)(ws + 82048);          //     81,920 B (ends    163,968; fully overwritten by A)
    Rec*      cand_rec = (Rec*)(ws + 163968);         // 20,971,520 B (ends 21,135,488; 32B-aligned base)
    ull*      img_keys = (ull*)(ws + 21135488);       //  2,097,152 B (ends 23,232,640)
    unsigned* img_meta = (unsigned*)(ws + 23232640);  //  1,048,576 B (ends 24,281,216)

    softmax_cand_kernel<<<(BB * RR) / 256, 256, 0, stream>>>(
        logits, box_reg, proposals, cand_rec, cnt_blk, (int*)ws);
    percls_kernel<<<BB * NC, 256, 0, stream>>>(
        cand_rec, cnt_blk, img_keys, img_meta, g_cnt, g_hist);
    topd_kernel<<<BB, 1024, 0, stream>>>(
        img_keys, img_meta, g_cnt, g_hist, box_reg, proposals, out);
}

// Round 12
// 190.306 us; speedup vs baseline: 1.3083x; 1.2994x over previous
//
#include <hip/hip_runtime.h>
#include <math.h>

#define BB   16
#define RR   4096
#define NC   80          // foreground classes
#define KK   300
#define DD   100
#define CCAP 512         // per-(image,class) candidate cap (expected ~118, sigma ~11)
#define CAP  16384       // per-image kept-candidate cap (expected ~8800)
#define LCAP 32          // per-(block,class) local cap in kernel A (lambda ~7.4)
#define NBLK 16          // kernel-A blocks per image (4096 rows / 256)
#define NW   5           // 5*64 = 320 >= KK bitmask words
#define PAD  (NW * 64)   // 320 padded rank slots
#define HBINS 1280       // score histogram bins (used: 1128)
#define HPT   5          // bins per scan-thread (1280/256)
#define BIN0  0x7A99u    // (0x3D4CCCCD >> 15): bin of score==0.05f
#define ZCNT  20512      // ints to zero in A: g_cnt(16)+pad(16)+g_hist(20480)

typedef unsigned long long ull;

__device__ __forceinline__ float4 decode_box(const float4 pr, const float4 rg) {
    float dx = rg.x / 10.0f;
    float dy = rg.y / 10.0f;
    float dw = fminf(rg.z / 5.0f, 4.135166556742356f);
    float dh = fminf(rg.w / 5.0f, 4.135166556742356f);
    float w  = pr.z - pr.x + 1.0f;
    float h  = pr.w - pr.y + 1.0f;
    float cx = pr.x + 0.5f * w;
    float cy = pr.y + 0.5f * h;
    float pcx = dx * w + cx;
    float pcy = dy * h + cy;
    float pw  = expf(dw) * w;
    float ph  = expf(dh) * h;
    float x1 = pcx - 0.5f * pw;
    float y1 = pcy - 0.5f * ph;
    float x2 = pcx + 0.5f * pw - 1.0f;
    float y2 = pcy + 0.5f * ph - 1.0f;
    x1 = fminf(fmaxf(x1, 0.0f), 1332.0f);
    y1 = fminf(fmaxf(y1, 0.0f), 799.0f);
    x2 = fminf(fmaxf(x2, 0.0f), 1332.0f);
    y2 = fminf(fmaxf(y2, 0.0f), 799.0f);
    return make_float4(x1, y1, x2, y2);
}

// ---- Kernel A: one lane per row, row in registers, SLIM 8B-key emit ----
// v[81] register-resident (launch_bounds(256,1): 1 wave/SIMD anyway, so the
// allocator may use ~512 VGPR -> no scratch). Serial max + serial left-fold
// expf sum in class order 0..80 (bit-identical). Emit path contains NO global
// loads and ~15 instrs/class: kills both the serialized box_reg gathers and
// the 16K-instruction I$ thrash that made R9-R11's fat emit 84 us.
__global__ __launch_bounds__(256, 1) void softmax_cand_kernel(
        const float* __restrict__ logits,
        ull*         __restrict__ cand_key,  // [BB*NC][NBLK][LCAP]
        int*         __restrict__ cnt_blk,   // [BB*NC][NBLK]
        int*         __restrict__ zeros) {   // ws head: ZCNT ints to clear
    __shared__ int lhist[NC];

    const int tid = threadIdx.x;
    const int gid = blockIdx.x * 256 + tid;
    const int b   = blockIdx.x >> 4;          // 16 blocks per image
    const int blk = blockIdx.x & 15;
    const int row = gid;                      // one thread per row

    if (gid < ZCNT) zeros[gid] = 0;

    if (tid < NC) lhist[tid] = 0;
    __syncthreads();

    const float* rp = logits + (size_t)row * 81;

    // single memory burst: 20 independent float4 loads + 1 scalar (MLP-20)
    float v[81];
    #pragma unroll
    for (int q = 0; q < 20; ++q) {
        float4 t = *(const float4*)(rp + 4 * q);
        v[4 * q + 0] = t.x; v[4 * q + 1] = t.y;
        v[4 * q + 2] = t.z; v[4 * q + 3] = t.w;
    }
    v[80] = rp[80];

    // serial max (exact)
    float m0 = -1e30f;
    #pragma unroll
    for (int c = 0; c < 81; ++c) m0 = fmaxf(m0, v[c]);

    // serial left-fold expf sum in class order 0..80 (bit-identical fold)
    float s0 = 0.0f;
    #pragma unroll
    for (int c = 0; c < 81; ++c) s0 += expf(v[c] - m0);

    // slim emit with conservative prefilter (margin >> libm ULP error)
    const float thr = logf(0.05f * s0) - 0.01f;
    const unsigned rlow = (unsigned)(row & 4095);

    #pragma unroll
    for (int c = 1; c < 81; ++c) {
        if (v[c] - m0 > thr) {
            float p = expf(v[c] - m0) / s0;   // exact expression as always
            if (p > 0.05f) {
                int ci  = c - 1;
                int pos = atomicAdd(&lhist[ci], 1);
                if (pos < LCAP)
                    cand_key[((size_t)(b * NC + ci) * NBLK + blk) * LCAP + pos] =
                        ((ull)__float_as_uint(p) << 32) | (unsigned)(~rlow);
            }
        }
    }
    __syncthreads();

    if (tid < NC) {
        int h = lhist[tid]; if (h > LCAP) h = LCAP;
        cnt_blk[(b * NC + tid) * NBLK + blk] = h;
    }
}

// ---- Kernel B: per (image,class): rank-by-count sort + WIDE gather+decode
//      (256 threads, 20 waves/CU -> latency hidden), parallel NMS mask build,
//      wave-0 greedy scan + append. Gather/decode verbatim from R4 (absmax 0). ----
__global__ __launch_bounds__(256) void percls_kernel(
        const ull*   __restrict__ cand_key,
        const int*   __restrict__ cnt_blk,
        const float* __restrict__ box_reg,
        const float* __restrict__ proposals,
        ull*         __restrict__ img_keys,  // [BB][CAP]
        unsigned*    __restrict__ img_meta,  // [BB][CAP]  (ci<<12 | r)
        int*         __restrict__ g_cnt,     // [BB]
        int*         __restrict__ g_hist) {  // [BB][HBINS]
    #pragma clang fp contract(off)
    __shared__ ull   keys[CCAP];                       // 4 KB   unsorted keys
    __shared__ ull   skey[PAD];                        // 2.56 KB rank-ordered keys
    __shared__ float bx1[PAD], by1[PAD], bx2[PAD], by2[PAD], bar[PAD];  // 6.4 KB
    __shared__ ull   supm[PAD * NW];                   // 12.8 KB per-row suppression masks
    __shared__ int   sbase[NBLK + 1];

    const int bid = blockIdx.x;     // 0..1279
    const int b   = bid / NC;
    const int ci  = bid % NC;
    const int tid = threadIdx.x;

    // wave-0 parallel prefix of the 16 per-A-block counts
    if (tid < 64) {
        int cnt = (tid < NBLK) ? cnt_blk[bid * NBLK + tid] : 0;
        int sc  = cnt;
        #pragma unroll
        for (int d = 1; d < NBLK; d <<= 1) {
            int o = __shfl_up(sc, d, NBLK);
            if ((tid & (NBLK - 1)) >= d) sc += o;
        }
        if (tid < NBLK) sbase[tid + 1] = sc;
        if (tid == 0)   sbase[0] = 0;
    }
    __syncthreads();

    int M = sbase[NBLK]; if (M > CCAP) M = CCAP;

    // flattened parallel segment compaction (coalesced key reads)
    for (int idx = tid; idx < NBLK * LCAP; idx += 256) {
        int seg = idx / LCAP, j = idx - seg * LCAP;
        int lo  = sbase[seg], c = sbase[seg + 1] - lo;
        if (j < c) {
            int slot = lo + j;
            if (slot < CCAP)
                keys[slot] = cand_key[(size_t)bid * (NBLK * LCAP) + idx];
        }
    }
    __syncthreads();

    const int N = (M < KK) ? M : KK;

    // rank-by-count + gather+decode + scatter (unique keys => exact sort).
    // 256 threads issue the random 16B reads -> high MLP at 20 waves/CU.
    for (int i = tid; i < M; i += 256) {
        ull ki = keys[i];
        int rank = 0;
        for (int j = 0; j < M; ++j) rank += (keys[j] > ki);  // broadcast LDS reads
        if (rank < PAD) {
            skey[rank] = ki;
            unsigned r = ~(unsigned)(ki & 0xFFFFFFFFu);
            size_t n = (size_t)b * RR + r;
            const float4 pr = *(const float4*)(proposals + n * 4);
            const float4 rg = *(const float4*)(box_reg + n * 324 + (size_t)(ci + 1) * 4);
            float4 bb = decode_box(pr, rg);
            bx1[rank] = bb.x; by1[rank] = bb.y; bx2[rank] = bb.z; by2[rank] = bb.w;
            bar[rank] = (bb.z - bb.x + 1.0f) * (bb.w - bb.y + 1.0f);
        }
    }
    __syncthreads();

    // parallel NMS mask build: thread per row i, IoU vs all j>i (identical math)
    for (int i = tid; i < N; i += 256) {
        ull mw[NW];
        #pragma unroll
        for (int w = 0; w < NW; ++w) mw[w] = 0ULL;
        const float ax1 = bx1[i], ay1 = by1[i],
                    ax2 = bx2[i], ay2 = by2[i], aar = bar[i];
        for (int j = i + 1; j < N; ++j) {
            float ltx = fmaxf(ax1, bx1[j]);
            float lty = fmaxf(ay1, by1[j]);
            float rbx = fminf(ax2, bx2[j]);
            float rby = fminf(ay2, by2[j]);
            float iw  = fmaxf(rbx - ltx + 1.0f, 0.0f);
            float ih  = fmaxf(rby - lty + 1.0f, 0.0f);
            float inter = iw * ih;
            float iou   = inter / ((aar + bar[j]) - inter);
            if (iou > 0.5f) mw[j >> 6] |= 1ULL << (j & 63);
        }
        #pragma unroll
        for (int w = 0; w < NW; ++w) supm[i * NW + w] = mw[w];
    }
    __syncthreads();

    // ---- greedy scan + append: wave 0, masks from LDS ----
    if (tid < 64) {
        const int lane = tid;

        ull keepw[NW];
        #pragma unroll
        for (int w = 0; w < NW; ++w) {
            int lo = w * 64;
            keepw[w] = (N >= lo + 64) ? ~0ULL : (N <= lo ? 0ULL : ((1ULL << (N - lo)) - 1ULL));
        }

        #pragma unroll
        for (int t = 0; t < NW; ++t) {
            if (t * 64 >= N) break;
            const int i = t * 64 + lane;
            ull sp[NW];
            #pragma unroll
            for (int w = 0; w < NW; ++w)
                sp[w] = (i < N) ? supm[i * NW + w] : 0ULL;

            ull rowany = 0ULL;
            #pragma unroll
            for (int w = 0; w < NW; ++w) rowany |= sp[w];
            const ull act = __ballot(rowany != 0ULL);

            ull mloop = keepw[t] & act;
            while (mloop) {
                int l = __builtin_ctzll(mloop);
                if ((keepw[t] >> l) & 1ULL) {
                    #pragma unroll
                    for (int w = 0; w < NW; ++w) {
                        if (w >= t && w * 64 < N)
                            keepw[w] &= ~__shfl(sp[w], l);
                    }
                }
                ull below = (l >= 63) ? ~0ULL : ((1ULL << (l + 1)) - 1ULL);
                mloop = keepw[t] & act & ~below;
            }
        }

        int total = 0;
        #pragma unroll
        for (int w = 0; w < NW; ++w) total += __popcll(keepw[w]);
        int base0 = 0;
        if (lane == 0) base0 = atomicAdd(&g_cnt[b], total);
        base0 = __shfl(base0, 0);

        int acc = 0;
        #pragma unroll
        for (int w = 0; w < NW; ++w) {
            if (w * 64 < N) {
                const ull km = keepw[w];
                const int k2 = w * 64 + lane;
                if ((km >> lane) & 1ULL) {
                    int rank = __popcll(km & ((1ULL << lane) - 1ULL));
                    int pos  = base0 + acc + rank;
                    if (pos < CAP) {
                        ull key = skey[k2];
                        unsigned sb = (unsigned)(key >> 32);
                        unsigned r  = ~(unsigned)(key & 0xFFFFFFFFu);
                        unsigned fi = (unsigned)(ci * KK + k2);
                        img_keys[(size_t)b * CAP + pos] =
                            ((ull)sb << 32) | (unsigned)(~fi);
                        img_meta[(size_t)b * CAP + pos] = ((unsigned)ci << 12) | (r & 4095u);
                        int bin = (int)((sb >> 15) - BIN0);
                        bin = (bin < 0) ? 0 : (bin >= HBINS ? HBINS - 1 : bin);
                        atomicAdd(&g_hist[b * HBINS + bin], 1);
                    }
                }
                acc += __popcll(km);
            }
        }
    }
}

// ---- Kernel C: threshold from prebuilt hist + gather + wave sort + emit (unchanged) ----
__global__ __launch_bounds__(1024) void topd_kernel(
        const ull*      __restrict__ img_keys,
        const unsigned* __restrict__ img_meta,
        const int*      __restrict__ g_cnt,
        const int*      __restrict__ g_hist,
        const float*    __restrict__ box_reg,
        const float*    __restrict__ proposals,
        float*          __restrict__ out) {
    __shared__ int  suf[256];
    __shared__ ull  pk[256];
    __shared__ int  ps[256];
    __shared__ int  sh_cnt, sh_tb;

    const int b   = blockIdx.x;
    const int tid = threadIdx.x;
    int M = g_cnt[b]; if (M > CAP) M = CAP;
    const ull* kp = img_keys + (size_t)b * CAP;
    const int* hh = g_hist + b * HBINS;

    if (tid == 0) { sh_cnt = 0; sh_tb = 0; }
    __syncthreads();

    int h[HPT], tot = 0;
    if (tid < 256) {
        #pragma unroll
        for (int r = 0; r < HPT; ++r) { h[r] = hh[tid * HPT + r]; tot += h[r]; }
        suf[tid] = tot;
    }
    __syncthreads();
    for (int off = 1; off < 256; off <<= 1) {
        int add = 0;
        if (tid < 256 && tid + off < 256) add = suf[tid + off];
        __syncthreads();
        if (tid < 256) suf[tid] += add;
        __syncthreads();
    }
    if (tid < 256) {
        int cum = suf[tid] - tot;
        #pragma unroll
        for (int jj = HPT - 1; jj >= 0; --jj) {
            int prev = cum;
            cum += h[jj];
            if (cum >= DD && prev < DD) sh_tb = tid * HPT + jj;
        }
    }
    __syncthreads();
    const unsigned keyLo = ((unsigned)sh_tb + BIN0) << 15;

    for (int i = tid; i < M; i += 1024) {
        ull key = kp[i];
        if ((unsigned)(key >> 32) >= keyLo) {
            int p = atomicAdd(&sh_cnt, 1);
            if (p < 256) { pk[p] = key; ps[p] = i; }
        }
    }
    __syncthreads();

    if (tid < 64) {
        const int lane  = tid;
        int ngath = sh_cnt; if (ngath > 256) ngath = 256;

        ull k4[4]; int s4[4];
        #pragma unroll
        for (int q = 0; q < 4; ++q) {
            int i = lane + 64 * q;
            bool vld = (i < ngath);
            k4[q] = vld ? pk[i] : 0ULL;
            s4[q] = vld ? ps[i] : -1;
        }

        #pragma unroll
        for (int k = 2; k <= 256; k <<= 1) {
            #pragma unroll
            for (int j = k >> 1; j > 0; j >>= 1) {
                if (j >= 64) {
                    const int qj = j >> 6;
                    #pragma unroll
                    for (int q = 0; q < 4; ++q) {
                        if ((q & qj) == 0 && (q + qj) < 4) {
                            int i0 = lane + 64 * q;
                            bool desc = ((i0 & k) == 0);
                            ull x = k4[q], y = k4[q + qj];
                            bool sw = desc ? (x < y) : (x > y);
                            if (sw) {
                                k4[q] = y; k4[q + qj] = x;
                                int t = s4[q]; s4[q] = s4[q + qj]; s4[q + qj] = t;
                            }
                        }
                    }
                } else {
                    #pragma unroll
                    for (int q = 0; q < 4; ++q) {
                        int i0 = lane + 64 * q;
                        bool desc  = ((i0 & k) == 0);
                        bool lower = ((lane & j) == 0);
                        ull pv = __shfl_xor(k4[q], j);
                        int sv = __shfl_xor(s4[q], j);
                        bool take = (desc == lower) ? (pv > k4[q]) : (pv < k4[q]);
                        if (take) { k4[q] = pv; s4[q] = sv; }
                    }
                }
            }
        }

        #pragma unroll
        for (int q = 0; q < 2; ++q) {
            int p = lane + 64 * q;
            if (p < DD) {
                float s; float4 bb; int label;
                if (p < ngath) {
                    ull key = k4[q];
                    unsigned fi   = ~(unsigned)(key & 0xFFFFFFFFu);
                    unsigned meta = img_meta[(size_t)b * CAP + s4[q]];
                    unsigned rr   = meta & 4095u;
                    unsigned ci   = meta >> 12;
                    s  = __uint_as_float((unsigned)(key >> 32));
                    size_t n = (size_t)b * RR + rr;
                    const float4 pr = *(const float4*)(proposals + n * 4);
                    const float4 rg = *(const float4*)(box_reg + n * 324 + (size_t)(ci + 1) * 4);
                    bb = decode_box(pr, rg);
                    label = (int)(fi / KK) + 1;
                } else {
                    s = -1.0f; bb = make_float4(0.0f, 0.0f, 0.0f, 0.0f); label = 0;
                }
                *(float4*)(out + (size_t)(b * DD + p) * 4) = bb;
                out[(size_t)BB * DD * 4 + b * DD + p] = s;
                out[(size_t)BB * DD * 4 + BB * DD + b * DD + p] = (float)label;
            }
        }
    }
}

extern "C" void kernel_launch(void* const* d_in, const int* in_sizes, int n_in,
                              void* d_out, int out_size, void* d_ws, size_t ws_size,
                              hipStream_t stream) {
    const float* logits    = (const float*)d_in[0];   // [B*R, 81]
    const float* box_reg   = (const float*)d_in[1];   // [B*R, 324]
    const float* proposals = (const float*)d_in[2];   // [B*R, 4]
    float* out = (float*)d_out;

    char* ws = (char*)d_ws;
    int*      g_cnt    = (int*)ws;                    //        64 B
    //        (ws + 64): 64 B reserved (zeroed, unused)
    int*      g_hist   = (int*)(ws + 128);            //    81,920 B (ends    82,048; first ZCNT ints zeroed by A)
    int*      cnt_blk  = (int*)(ws + 82048);          //    81,920 B (ends   163,968; fully overwritten by A)
    ull*      cand_key = (ull*)(ws + 163968);         // 5,242,880 B (ends 5,406,848)
    ull*      img_keys = (ull*)(ws + 5406848);        // 2,097,152 B (ends 7,504,000)
    unsigned* img_meta = (unsigned*)(ws + 7504000);   // 1,048,576 B (ends 8,552,576)

    softmax_cand_kernel<<<(BB * RR) / 256, 256, 0, stream>>>(
        logits, cand_key, cnt_blk, (int*)ws);
    percls_kernel<<<BB * NC, 256, 0, stream>>>(
        cand_key, cnt_blk, box_reg, proposals, img_keys, img_meta, g_cnt, g_hist);
    topd_kernel<<<BB, 1024, 0, stream>>>(
        img_keys, img_meta, g_cnt, g_hist, box_reg, proposals, out);
}